// Round 4
// baseline (159.774 us; speedup 1.0000x reference)
//
#include <hip/hip_runtime.h>

#define BB 4
#define NN 4096        // 64*64 spatial
#define CQK 64
#define DQ 16
#define CV 128

typedef __attribute__((ext_vector_type(8))) short bf16x8;
typedef __attribute__((ext_vector_type(4))) float f32x4;
typedef __attribute__((ext_vector_type(16))) float f32x16;
typedef __attribute__((ext_vector_type(8))) unsigned short u16x8;
typedef __attribute__((ext_vector_type(4))) unsigned int u32x4;

__device__ __forceinline__ unsigned short f2bf(float f) {
    unsigned int u = __builtin_bit_cast(unsigned int, f);
    u += 0x7FFFu + ((u >> 16) & 1u);   // RNE
    return (unsigned short)(u >> 16);
}
__device__ __forceinline__ unsigned int pk2bf(float a, float b) {
    return (unsigned int)f2bf(a) | ((unsigned int)f2bf(b) << 16);
}
__device__ __forceinline__ float bf2f(unsigned short u) {
    return __builtin_bit_cast(float, (unsigned int)u << 16);
}
// truncation-pack two fp32 -> packed bf16x2 (v_perm_b32-foldable)
__device__ __forceinline__ unsigned int pk_trunc(float lo, float hi) {
    unsigned int a = __builtin_bit_cast(unsigned int, lo);
    unsigned int b = __builtin_bit_cast(unsigned int, hi);
    return (a >> 16) | (b & 0xFFFF0000u);
}

// ================= fused projections =================
// blocks 0..63:    Q/K projection (256 positions per block) -- FIRST so they
//                  overlap the V blocks instead of trailing as a tail.
// blocks 64..575:  V projection (2 blocks per 64-pos tile, 64 out-chans each)
__global__ __launch_bounds__(256, 4) void proj(
    const float* __restrict__ x,   // [B][64][N]
    const float* __restrict__ Wq, const float* __restrict__ bq,
    const float* __restrict__ Wk, const float* __restrict__ bk,
    const float* __restrict__ xh,  // [B][128][N]
    const float* __restrict__ Wv, const float* __restrict__ bv,
    unsigned short* __restrict__ qT, unsigned short* __restrict__ kT,
    unsigned short* __restrict__ vB)
{
    __shared__ __align__(16) float smem[8448];
    int tid = threadIdx.x;
    if (blockIdx.x >= 64) {
        // ---------- V projection ----------
        float* wvT = smem;            // [64 ci][66]
        float* xs  = smem + 4224;     // [64 ci][64 pos]
        float* bvs = smem + 8320;     // [64]
        int bid = blockIdx.x - 64;
        int pt = bid >> 1, h = bid & 1;
        int i0 = pt * 64;
        int b = i0 >> 12, ib = i0 & 4095;
        int co0 = h * 64;
        if (tid < 64) bvs[tid] = bv[co0 + tid];
        int cog = tid & 31, ig = tid >> 5;   // 2 out-chans, 8 positions
        float acc[8][2];
#pragma unroll
        for (int q = 0; q < 8; q++) { acc[q][0] = 0.f; acc[q][1] = 0.f; }

        for (int ch = 0; ch < 2; ch++) {
            for (int t = tid; t < 4096; t += 256) {
                int c = t & 63, col = t >> 6;
                wvT[c * 66 + col] = Wv[(size_t)(co0 + col) * CV + ch * 64 + c];
            }
            for (int t = tid; t < 4096; t += 256) {
                int il = t & 63, c = t >> 6;
                xs[c * 64 + il] = xh[((size_t)b * CV + ch * 64 + c) * NN + ib + il];
            }
            __syncthreads();
            for (int c = 0; c < 64; c++) {
                float2 w2 = *(const float2*)&wvT[c * 66 + cog * 2];
                float4 xa = *(const float4*)&xs[c * 64 + ig * 8];
                float4 xb = *(const float4*)&xs[c * 64 + ig * 8 + 4];
                float xv[8] = { xa.x, xa.y, xa.z, xa.w, xb.x, xb.y, xb.z, xb.w };
#pragma unroll
                for (int q = 0; q < 8; q++) {
                    acc[q][0] += xv[q] * w2.x;
                    acc[q][1] += xv[q] * w2.y;
                }
            }
            __syncthreads();
        }
        // swizzled store: vB per 64-key tile holds 16 A-frags for
        // v_mfma_f32_32x32x16_bf16 (A = V, m=channel, k=key-in-chunk):
        //   frag i = g*4 + kchunk   (g = chan group of 32, kchunk = key/16)
        //   lane   = (co&31) + 32*((key>>3)&1)   (A: m=lane&31, k=8*(lane>>5)+j)
        //   elem j = key & 7
        int kt = ib >> 6;
        int hb = ig & 1, kc = ig >> 1;   // keys ig*8..ig*8+7 -> chunk kc, half hb
#pragma unroll
        for (int cc = 0; cc < 2; cc++) {
            int co = co0 + cog * 2 + cc;
            int g = co >> 5, cl = co & 31;
            float bb = bvs[cog * 2 + cc];
            u16x8 o;
#pragma unroll
            for (int jj = 0; jj < 8; jj++) o[jj] = f2bf(acc[jj][cc] + bb);
            size_t base = ((size_t)(b * 64 + kt)) * 8192
                        + (size_t)(((g * 4 + kc) * 64 + hb * 32 + cl)) * 8;
            *(u16x8*)(vB + base) = o;
        }
    } else {
        // ---------- Q/K projection ----------
        float* wqT = smem;          // [64 c][16 d]
        float* wkT = smem + 1024;
        float* bqs = smem + 2048;
        float* bks = smem + 2064;
        for (int t = tid; t < 1024; t += 256) {
            int c = t & 63, d = t >> 6;          // coalesced global read
            wqT[c * 16 + d] = Wq[d * CQK + c];
            wkT[c * 16 + d] = Wk[d * CQK + c];
        }
        if (tid < DQ) { bqs[tid] = bq[tid]; bks[tid] = bk[tid]; }
        __syncthreads();

        int gidx = blockIdx.x * 256 + tid;   // over B*N
        int b = gidx >> 12, i = gidx & 4095;
        float qa[DQ], ka[DQ];
#pragma unroll
        for (int d = 0; d < DQ; d++) { qa[d] = bqs[d]; ka[d] = bks[d]; }
        const float* xp = x + (size_t)b * CQK * NN + i;
        for (int c = 0; c < CQK; c++) {
            float xv = xp[(size_t)c * NN];
            const float4* wq4 = (const float4*)&wqT[c * DQ];
            const float4* wk4 = (const float4*)&wkT[c * DQ];
#pragma unroll
            for (int dd = 0; dd < 4; dd++) {
                float4 a = wq4[dd], e = wk4[dd];
                qa[dd*4+0] += a.x * xv; qa[dd*4+1] += a.y * xv;
                qa[dd*4+2] += a.z * xv; qa[dd*4+3] += a.w * xv;
                ka[dd*4+0] += e.x * xv; ka[dd*4+1] += e.y * xv;
                ka[dd*4+2] += e.z * xv; ka[dd*4+3] += e.w * xv;
            }
        }
        u16x8 q0, q1, k0, k1;
#pragma unroll
        for (int dd = 0; dd < 8; dd++) {
            q0[dd] = f2bf(qa[dd]);     q1[dd] = f2bf(qa[8 + dd]);
            k0[dd] = f2bf(ka[dd]);     k1[dd] = f2bf(ka[8 + dd]);
        }
        u16x8* qo = (u16x8*)(qT + (size_t)gidx * DQ);
        u16x8* ko = (u16x8*)(kT + (size_t)gidx * DQ);
        qo[0] = q0; qo[1] = q1;
        ko[0] = k0; ko[1] = k1;
    }
}

// ============ MFMA flash attention, 64 queries/block, 8 waves ============
// 64q/block halves per-query V traffic (512MB -> 256MB L2 reads; that BW
// was the R2 floor). GRID MUST BE BB*64=256 (R3 crash: launched 512 ->
// qg up to 127 -> i0 8128 > 4032 -> OOB out[] writes -> core dump).
// Wave w owns key tiles w*8..w*8+7; both 32-q groups (A=q 0..31, B=32..63)
// share kb (QK^T) and vc (PV) fragments.
// S^T = K.Q^T per group; P B-frags built in-register via pk_trunc +
// v_permlane32_swap_b32 (R2-verified: swap(D,S): D.hi <-> S.lo).
// vc0/vc1 explicit ping-pong (NO runtime-indexed reg arrays -> no scratch).
// Merge: each wave writes its 64qx128c partial as bf16 to its own LDS slab
// (pad-132 rows: stride 264B -> 2-way-free banks), ONE barrier, epilogue
// sums 8 slabs. Adds ~0.2% rel on O partials (threshold has 3x headroom).
// XCD swizzle: p -> b=(p>>1)&3, qg=((p>>3)<<1)|(p&1) (bijective on [0,256));
// p&7 fixes (b,lo) so each XCD re-reads ONE batch's V (1MB hot < 4MB L2).
// Register budget: acc 128 + pA/pB 32 + vc 32 + kb/qa 16 + s transient
// ~= 240-255; (512,2) caps at 256 for 2 waves/SIMD (8 waves/CU, as R2).
__global__ __launch_bounds__(512, 2) void flash_mfma(
    const unsigned short* __restrict__ qTb,  // [B*N][16] bf16
    const unsigned short* __restrict__ kTb,  // [B*N][16] bf16
    const unsigned short* __restrict__ vB,   // swizzled bf16 (32x32 A-frag order)
    const float* __restrict__ xh,            // [B][128][N]
    const float* __restrict__ gamma,
    float* __restrict__ out)                 // [B][128][N]
{
    __shared__ __align__(16) unsigned short part[8 * 64 * 132]; // 135168 B
    __shared__ float l_s[16 * 64];                              // 4096 B

    int tid = threadIdx.x;
    int w = tid >> 6, lane = tid & 63;
    int q32 = lane & 31, half = lane >> 5;
    int p = blockIdx.x;
    int b = (p >> 1) & 3;
    int qg = ((p >> 3) << 1) | (p & 1);
    int i0 = qg * 64;
    f32x16 zf16;
#pragma unroll
    for (int r = 0; r < 16; r++) zf16[r] = 0.f;

    // Q B-frags (32x32x16): B[k=half*8+j][n=q32], groups A (q 0..31), B (32..63)
    bf16x8 qaA = *(const bf16x8*)(qTb + ((size_t)(b * NN + i0 + q32)) * DQ + half * 8);
    bf16x8 qaB = *(const bf16x8*)(qTb + ((size_t)(b * NN + i0 + 32 + q32)) * DQ + half * 8);

    f32x16 accA[4], accB[4];   // O^T[c][q]: c = g*32+(reg&3)+8*(reg>>2)+4*half
#pragma unroll
    for (int g = 0; g < 4; g++) { accA[g] = zf16; accB[g] = zf16; }
    float lA = 0.f, lB = 0.f;

    const unsigned short* vtile = vB + ((size_t)(b * 64 + w * 8)) * 8192;
    const unsigned short* kbase = kTb + ((size_t)(b * NN + w * 8 * 64)) * DQ;

    // prefetch tile 0: K A-frags (A[m=key=q32][k=half*8+j]) + chunk0 V frags
    bf16x8 kb[2], vc0[4], vc1[4];
#pragma unroll
    for (int mg = 0; mg < 2; mg++)
        kb[mg] = *(const bf16x8*)(kbase + (size_t)(mg * 32 + q32) * DQ + half * 8);
#pragma unroll
    for (int g = 0; g < 4; g++)
        vc0[g] = *(const bf16x8*)(vtile + (size_t)(g * 4) * 512 + (size_t)lane * 8);

#define PACK_GRP(S0, S1, P, LACC)                                            \
    _Pragma("unroll")                                                        \
    for (int u = 0; u < 4; u++) {                                            \
        const f32x16& sv = (u >> 1) ? (S1) : (S0);                           \
        const int h8 = (u & 1) * 8;                                          \
        float p0 = __expf(sv[h8 + 0]), p1 = __expf(sv[h8 + 1]);              \
        float p2 = __expf(sv[h8 + 2]), p3 = __expf(sv[h8 + 3]);              \
        float p4 = __expf(sv[h8 + 4]), p5 = __expf(sv[h8 + 5]);              \
        float p6 = __expf(sv[h8 + 6]), p7 = __expf(sv[h8 + 7]);              \
        LACC += ((p0 + p1) + (p2 + p3)) + ((p4 + p5) + (p6 + p7));           \
        unsigned int A0 = pk_trunc(p0, p1), A1 = pk_trunc(p2, p3);           \
        unsigned int A2 = pk_trunc(p4, p5), A3 = pk_trunc(p6, p7);           \
        asm("v_permlane32_swap_b32 %0, %1" : "+v"(A0), "+v"(A2));            \
        asm("v_permlane32_swap_b32 %0, %1" : "+v"(A1), "+v"(A3));            \
        P[u] = (u32x4){A0, A1, A2, A3};                                      \
    }

#define PV_STEP(VCUR, VNXT, U)                                               \
    {                                                                        \
        const unsigned short* src = ((U) < 3) ? vtile : vtn;                 \
        const int uu = ((U) + 1) & 3;                                        \
        _Pragma("unroll")                                                    \
        for (int g = 0; g < 4; g++)                                          \
            VNXT[g] = *(const bf16x8*)(src + (size_t)(g * 4 + uu) * 512      \
                                           + (size_t)lane * 8);              \
        bf16x8 pa = __builtin_bit_cast(bf16x8, pA[U]);                       \
        bf16x8 pbv = __builtin_bit_cast(bf16x8, pB[U]);                      \
        __builtin_amdgcn_s_setprio(1);                                       \
        _Pragma("unroll")                                                    \
        for (int g = 0; g < 4; g++) {                                        \
            accA[g] = __builtin_amdgcn_mfma_f32_32x32x16_bf16(VCUR[g], pa, accA[g], 0, 0, 0);  \
            accB[g] = __builtin_amdgcn_mfma_f32_32x32x16_bf16(VCUR[g], pbv, accB[g], 0, 0, 0); \
        }                                                                    \
        __builtin_amdgcn_s_setprio(0);                                       \
    }

    for (int t = 0; t < 8; t++) {
        // --- group A: S^T = K.Q^T, exp, pack (sA dies before sB is made) ---
        f32x16 sA0 = __builtin_amdgcn_mfma_f32_32x32x16_bf16(kb[0], qaA, zf16, 0, 0, 0);
        f32x16 sA1 = __builtin_amdgcn_mfma_f32_32x32x16_bf16(kb[1], qaA, zf16, 0, 0, 0);
        u32x4 pA[4];
        PACK_GRP(sA0, sA1, pA, lA)
        // --- group B (kb still holds current tile) ---
        f32x16 sB0 = __builtin_amdgcn_mfma_f32_32x32x16_bf16(kb[0], qaB, zf16, 0, 0, 0);
        f32x16 sB1 = __builtin_amdgcn_mfma_f32_32x32x16_bf16(kb[1], qaB, zf16, 0, 0, 0);
        const unsigned short* ktn = kbase + (size_t)(((t + 1) & 7) * 64) * DQ;
#pragma unroll
        for (int mg = 0; mg < 2; mg++)
            kb[mg] = *(const bf16x8*)(ktn + (size_t)(mg * 32 + q32) * DQ + half * 8);
        u32x4 pB[4];
        PACK_GRP(sB0, sB1, pB, lB)

        const unsigned short* vtn = vtile + ((t < 7) ? 8192 : 0);
        // --- PV: 4 chunks x (4 chan-groups x 2 q-groups) MFMAs, vb shared ---
        PV_STEP(vc0, vc1, 0)
        PV_STEP(vc1, vc0, 1)
        PV_STEP(vc0, vc1, 2)
        PV_STEP(vc1, vc0, 3)
        vtile = vtn;
    }

    // --- merge: bf16 partials, one slab per wave, ONE barrier ---
    l_s[(w * 2 + half) * 64 + q32] = lA;
    l_s[(w * 2 + half) * 64 + 32 + q32] = lB;
    unsigned short* pw = part + (size_t)w * (64 * 132);
#pragma unroll
    for (int g = 0; g < 4; g++)
#pragma unroll
        for (int r = 0; r < 4; r++) {
            int colb = g * 32 + r * 8 + half * 4;
            uint2 da = { pk2bf(accA[g][r * 4 + 0], accA[g][r * 4 + 1]),
                         pk2bf(accA[g][r * 4 + 2], accA[g][r * 4 + 3]) };
            uint2 db = { pk2bf(accB[g][r * 4 + 0], accB[g][r * 4 + 1]),
                         pk2bf(accB[g][r * 4 + 2], accB[g][r * 4 + 3]) };
            *(uint2*)(pw + q32 * 132 + colb) = da;
            *(uint2*)(pw + (32 + q32) * 132 + colb) = db;
        }
    __syncthreads();

    // --- epilogue: 512 threads, q = tid&63, 16 channels each ---
    float gam = gamma[0];
    int q = tid & 63, cg = tid >> 6;
    float L = 0.f;
#pragma unroll
    for (int e = 0; e < 16; e++) L += l_s[e * 64 + q];
    float linv = 1.f / L;
    float o[16];
#pragma unroll
    for (int cc = 0; cc < 16; cc++) o[cc] = 0.f;
#pragma unroll
    for (int e = 0; e < 8; e++) {
        const unsigned short* pr = part + (size_t)e * (64 * 132) + q * 132 + cg * 16;
        u16x8 v0 = *(const u16x8*)pr;
        u16x8 v1 = *(const u16x8*)(pr + 8);
#pragma unroll
        for (int j = 0; j < 8; j++) { o[j] += bf2f(v0[j]); o[8 + j] += bf2f(v1[j]); }
    }
#pragma unroll
    for (int cc = 0; cc < 16; cc++) {
        int c = cg * 16 + cc;
        size_t gi = ((size_t)(b * CV + c)) * NN + i0 + q;
        out[gi] = gam * o[cc] * linv + xh[gi];
    }
}

extern "C" void kernel_launch(void* const* d_in, const int* in_sizes, int n_in,
                              void* d_out, int out_size, void* d_ws, size_t ws_size,
                              hipStream_t stream)
{
    (void)in_sizes; (void)n_in; (void)out_size; (void)ws_size;
    const float* x  = (const float*)d_in[0];
    const float* xh = (const float*)d_in[1];
    const float* Wq = (const float*)d_in[2];
    const float* bq = (const float*)d_in[3];
    const float* Wk = (const float*)d_in[4];
    const float* bk = (const float*)d_in[5];
    const float* Wv = (const float*)d_in[6];
    const float* bv = (const float*)d_in[7];
    const float* gm = (const float*)d_in[8];
    float* out = (float*)d_out;

    char* ws = (char*)d_ws;
    unsigned short* qTb = (unsigned short*)ws;                      // 512 KB
    unsigned short* kTb = (unsigned short*)(ws + (512 << 10));      // 512 KB
    unsigned short* vB  = (unsigned short*)(ws + (1 << 20));        // 4 MB

    proj<<<576, 256, 0, stream>>>(x, Wq, bq, Wk, bk, xh, Wv, bv, qTb, kTb, vB);
    // 64 queries/block -> BB*64 = 256 blocks (NOT BB*128; R3 OOB crash)
    flash_mfma<<<BB * 64, 512, 0, stream>>>(qTb, kTb, vB, xh, gm, out);
}

// Round 5
// 129.754 us; speedup vs baseline: 1.2314x; 1.2314x over previous
//
#include <hip/hip_runtime.h>

#define BB 4
#define NN 4096        // 64*64 spatial
#define CQK 64
#define DQ 16
#define CV 128

typedef __attribute__((ext_vector_type(8))) short bf16x8;
typedef __attribute__((ext_vector_type(4))) float f32x4;
typedef __attribute__((ext_vector_type(16))) float f32x16;
typedef __attribute__((ext_vector_type(8))) unsigned short u16x8;
typedef __attribute__((ext_vector_type(4))) unsigned int u32x4;

__device__ __forceinline__ unsigned short f2bf(float f) {
    unsigned int u = __builtin_bit_cast(unsigned int, f);
    u += 0x7FFFu + ((u >> 16) & 1u);   // RNE
    return (unsigned short)(u >> 16);
}
__device__ __forceinline__ unsigned int pk2bf(float a, float b) {
    return (unsigned int)f2bf(a) | ((unsigned int)f2bf(b) << 16);
}
// truncation-pack two fp32 -> packed bf16x2 (v_perm_b32-foldable)
__device__ __forceinline__ unsigned int pk_trunc(float lo, float hi) {
    unsigned int a = __builtin_bit_cast(unsigned int, lo);
    unsigned int b = __builtin_bit_cast(unsigned int, hi);
    return (a >> 16) | (b & 0xFFFF0000u);
}

// ================= fused projections =================
// blocks 0..63:    Q/K projection (256 positions per block), fp32 VALU path.
// blocks 64..319:  V projection via MFMA (R5 rewrite; old VALU V-proj was
//                  ~40us of the 121us total -- 10x over its roofline).
//   One block per 64-key vB tile (256 = B*64). V = Wv(128x128) . xh(128xN)
//   computed in bf16 MFMA (fp32 accum): A = xh (m=pos, k=cin, 8 coalesced
//   4B loads per frag), B = Wv (k=cin, n=co, contiguous float4 pairs).
//   C-layout col=co, row=pos[(r&3)+8*(r>>2)+4h] -> vB A-frag layout via the
//   R2-PROVEN pk + v_permlane32_swap_b32 pattern (D.hi <-> S.lo), so vB is
//   bit-identical in layout to what flash_mfma consumes (unchanged).
//   4 waves = (pos-tile pt 0..1) x (co-half gh 0..1); 16 MFMA/wave; no LDS.
__global__ __launch_bounds__(256, 4) void proj(
    const float* __restrict__ x,   // [B][64][N]
    const float* __restrict__ Wq, const float* __restrict__ bq,
    const float* __restrict__ Wk, const float* __restrict__ bk,
    const float* __restrict__ xh,  // [B][128][N]
    const float* __restrict__ Wv, const float* __restrict__ bv,
    unsigned short* __restrict__ qT, unsigned short* __restrict__ kT,
    unsigned short* __restrict__ vB)
{
    __shared__ __align__(16) float smem[2112];
    int tid = threadIdx.x;
    if (blockIdx.x >= 64) {
        // ---------- V projection (MFMA) ----------
        int bid = blockIdx.x - 64;            // 0..255
        int b = bid >> 6, kt = bid & 63;
        int lane = tid & 63, w = tid >> 6;
        int pt = w & 1, gh = w >> 1;          // pos-tile, co-half
        int cl = lane & 31, kh = lane >> 5;
        int pos = kt * 64 + pt * 32 + cl;     // this lane's A-column (m)
        const float* xb = xh + (size_t)b * CV * NN;
        f32x16 zf16;
#pragma unroll
        for (int r = 0; r < 16; r++) zf16[r] = 0.f;
        f32x16 c0 = zf16, c1 = zf16;          // co groups g0=gh*2, g1=gh*2+1
        float bv0 = bv[(gh * 2 + 0) * 32 + cl];
        float bv1 = bv[(gh * 2 + 1) * 32 + cl];

#pragma unroll
        for (int kc = 0; kc < 8; ++kc) {
            int cin0 = kc * 16 + kh * 8;
            // A-frag: xh[cin0+j][pos], j=0..7 (each j: 32 lanes coalesced)
            const float* xc = xb + (size_t)cin0 * NN + pos;
            float f0 = xc[0 * NN], f1 = xc[1 * NN], f2 = xc[2 * NN], f3 = xc[3 * NN];
            float f4 = xc[4 * NN], f5 = xc[5 * NN], f6 = xc[6 * NN], f7 = xc[7 * NN];
            u32x4 aw = { pk_trunc(f0, f1), pk_trunc(f2, f3),
                         pk_trunc(f4, f5), pk_trunc(f6, f7) };
            bf16x8 af = __builtin_bit_cast(bf16x8, aw);
            // B-frags: Wv[co][cin0..cin0+7] contiguous
            const float* wp0 = Wv + (size_t)((gh * 2 + 0) * 32 + cl) * CV + cin0;
            float4 wa = *(const float4*)wp0, wb_ = *(const float4*)(wp0 + 4);
            u32x4 bw0 = { pk_trunc(wa.x, wa.y), pk_trunc(wa.z, wa.w),
                          pk_trunc(wb_.x, wb_.y), pk_trunc(wb_.z, wb_.w) };
            const float* wp1 = Wv + (size_t)((gh * 2 + 1) * 32 + cl) * CV + cin0;
            float4 wc = *(const float4*)wp1, wd = *(const float4*)(wp1 + 4);
            u32x4 bw1 = { pk_trunc(wc.x, wc.y), pk_trunc(wc.z, wc.w),
                          pk_trunc(wd.x, wd.y), pk_trunc(wd.z, wd.w) };
            c0 = __builtin_amdgcn_mfma_f32_32x32x16_bf16(
                     af, __builtin_bit_cast(bf16x8, bw0), c0, 0, 0, 0);
            c1 = __builtin_amdgcn_mfma_f32_32x32x16_bf16(
                     af, __builtin_bit_cast(bf16x8, bw1), c1, 0, 0, 0);
        }

        size_t tb = (size_t)(b * 64 + kt) * 8192;
        // pack C (+bias, RNE) -> vB A-frags; same swap pattern as flash P.
#define EMIT_G(CVEC, G, BVV)                                                 \
        {                                                                    \
            unsigned int A0 = pk2bf(CVEC[0] + BVV, CVEC[1] + BVV);           \
            unsigned int A1 = pk2bf(CVEC[2] + BVV, CVEC[3] + BVV);           \
            unsigned int A2 = pk2bf(CVEC[4] + BVV, CVEC[5] + BVV);           \
            unsigned int A3 = pk2bf(CVEC[6] + BVV, CVEC[7] + BVV);           \
            asm("v_permlane32_swap_b32 %0, %1" : "+v"(A0), "+v"(A2));        \
            asm("v_permlane32_swap_b32 %0, %1" : "+v"(A1), "+v"(A3));        \
            *(u32x4*)(vB + tb + (size_t)((G) * 4 + pt * 2) * 512             \
                         + (size_t)lane * 8) = (u32x4){A0, A1, A2, A3};      \
            unsigned int B0 = pk2bf(CVEC[8] + BVV, CVEC[9] + BVV);           \
            unsigned int B1 = pk2bf(CVEC[10] + BVV, CVEC[11] + BVV);         \
            unsigned int B2 = pk2bf(CVEC[12] + BVV, CVEC[13] + BVV);         \
            unsigned int B3 = pk2bf(CVEC[14] + BVV, CVEC[15] + BVV);         \
            asm("v_permlane32_swap_b32 %0, %1" : "+v"(B0), "+v"(B2));        \
            asm("v_permlane32_swap_b32 %0, %1" : "+v"(B1), "+v"(B3));        \
            *(u32x4*)(vB + tb + (size_t)((G) * 4 + pt * 2 + 1) * 512         \
                         + (size_t)lane * 8) = (u32x4){B0, B1, B2, B3};      \
        }
        EMIT_G(c0, gh * 2 + 0, bv0)
        EMIT_G(c1, gh * 2 + 1, bv1)
#undef EMIT_G
    } else {
        // ---------- Q/K projection ----------
        float* wqT = smem;          // [64 c][16 d]
        float* wkT = smem + 1024;
        float* bqs = smem + 2048;
        float* bks = smem + 2064;
        for (int t = tid; t < 1024; t += 256) {
            int c = t & 63, d = t >> 6;          // coalesced global read
            wqT[c * 16 + d] = Wq[d * CQK + c];
            wkT[c * 16 + d] = Wk[d * CQK + c];
        }
        if (tid < DQ) { bqs[tid] = bq[tid]; bks[tid] = bk[tid]; }
        __syncthreads();

        int gidx = blockIdx.x * 256 + tid;   // over B*N
        int b = gidx >> 12, i = gidx & 4095;
        float qa[DQ], ka[DQ];
#pragma unroll
        for (int d = 0; d < DQ; d++) { qa[d] = bqs[d]; ka[d] = bks[d]; }
        const float* xp = x + (size_t)b * CQK * NN + i;
        for (int c = 0; c < CQK; c++) {
            float xv = xp[(size_t)c * NN];
            const float4* wq4 = (const float4*)&wqT[c * DQ];
            const float4* wk4 = (const float4*)&wkT[c * DQ];
#pragma unroll
            for (int dd = 0; dd < 4; dd++) {
                float4 a = wq4[dd], e = wk4[dd];
                qa[dd*4+0] += a.x * xv; qa[dd*4+1] += a.y * xv;
                qa[dd*4+2] += a.z * xv; qa[dd*4+3] += a.w * xv;
                ka[dd*4+0] += e.x * xv; ka[dd*4+1] += e.y * xv;
                ka[dd*4+2] += e.z * xv; ka[dd*4+3] += e.w * xv;
            }
        }
        u16x8 q0, q1, k0, k1;
#pragma unroll
        for (int dd = 0; dd < 8; dd++) {
            q0[dd] = f2bf(qa[dd]);     q1[dd] = f2bf(qa[8 + dd]);
            k0[dd] = f2bf(ka[dd]);     k1[dd] = f2bf(ka[8 + dd]);
        }
        u16x8* qo = (u16x8*)(qT + (size_t)gidx * DQ);
        u16x8* ko = (u16x8*)(kT + (size_t)gidx * DQ);
        qo[0] = q0; qo[1] = q1;
        ko[0] = k0; ko[1] = k1;
    }
}

// ================= MFMA flash attention, 32 queries/block =================
// EXACT R2 champion (121.3us total, flash ~36us). 64q variant (R4) spilled:
// VGPR 128+128 AGPR full, 150MB scratch writes, 74us -- reverted.
// block = one 32-query group; wave w owns key tiles w*16..w*16+15 (split-K).
// QK^T via v_mfma_f32_32x32x16_bf16 (K=16 exact): S^T = K.Q^T,
// C: col=lane&31=q, row=key=(reg&3)+8*(reg>>2)+4*(lane>>5).
// PV via 4x v_mfma_f32_32x32x16_bf16 per 16-key chunk: A = V, B = P built
// in-register via pk_trunc + v_permlane32_swap_b32 (D.hi <-> S.lo).
// (256,2): do NOT raise min-waves (R7 spill lesson). 32q/block optimum (R11).
__global__ __launch_bounds__(256, 2) void flash_mfma(
    const unsigned short* __restrict__ qTb,  // [B*N][16] bf16
    const unsigned short* __restrict__ kTb,  // [B*N][16] bf16
    const unsigned short* __restrict__ vB,   // swizzled bf16 (32x32 A-frag order)
    const float* __restrict__ xh,            // [B][128][N]
    const float* __restrict__ gamma,
    float* __restrict__ out)                 // [B][128][N]
{
    __shared__ __align__(16) float accs[32 * 132];   // [q 32][c pad132]
    __shared__ float l_s[4 * 2 * 32];                // [w][half][q]

    int tid = threadIdx.x;
    int w = tid >> 6, lane = tid & 63;
    int q32 = lane & 31, half = lane >> 5;
    int b = blockIdx.x >> 7;                  // 128 q-groups of 32 per batch
    int i0 = (blockIdx.x & 127) * 32;
    f32x16 zf16;
#pragma unroll
    for (int r = 0; r < 16; r++) zf16[r] = 0.f;

    // Q B-frag (32x32x16): B[k=half*8+j][n=q32]
    bf16x8 qa = *(const bf16x8*)(qTb + ((size_t)(b * NN + i0 + q32)) * DQ + half * 8);

    f32x16 acc[4];                            // O^T[c][q]: c = g*32+(reg&3)+8*(reg>>2)+4*half
#pragma unroll
    for (int g = 0; g < 4; g++) acc[g] = zf16;
    float l = 0.f;

    const unsigned short* vtile = vB + ((size_t)(b * 64 + w * 16)) * 8192;
    const unsigned short* kbase = kTb + ((size_t)(b * NN + w * 16 * 64)) * DQ;

    // prefetch tile 0: K A-frags (A[m=key=q32][k=half*8+j]) + 16 V A-frags
    bf16x8 kb[2], vb[16];
#pragma unroll
    for (int mg = 0; mg < 2; mg++)
        kb[mg] = *(const bf16x8*)(kbase + (size_t)(mg * 32 + q32) * DQ + half * 8);
#pragma unroll
    for (int i = 0; i < 16; i++)
        vb[i] = *(const bf16x8*)(vtile + (size_t)i * 512 + (size_t)lane * 8);

    for (int t = 0; t < 16; t++) {
        // --- S^T = K.Q^T : two 32x32x16 (keys 0-31, 32-63) x 32 queries ---
        f32x16 s[2];
        s[0] = __builtin_amdgcn_mfma_f32_32x32x16_bf16(kb[0], qa, zf16, 0, 0, 0);
        s[1] = __builtin_amdgcn_mfma_f32_32x32x16_bf16(kb[1], qa, zf16, 0, 0, 0);
        const unsigned short* ktn = kbase + (size_t)(((t + 1) & 15) * 64) * DQ;
#pragma unroll
        for (int mg = 0; mg < 2; mg++)
            kb[mg] = *(const bf16x8*)(ktn + (size_t)(mg * 32 + q32) * DQ + half * 8);

        const unsigned short* vtn = vtile + ((t < 15) ? 8192 : 0);
        // --- per 16-key chunk: exp -> in-register B-frag -> 4 PV MFMAs ---
#pragma unroll
        for (int u = 0; u < 4; u++) {
            const int mg = u >> 1, h8 = (u & 1) * 8;
            // lane (q,half) holds keys-in-chunk {0..3}+4h (p0-3), {8..11}+4h (p4-7)
            float p0 = __expf(s[mg][h8 + 0]);
            float p1 = __expf(s[mg][h8 + 1]);
            float p2 = __expf(s[mg][h8 + 2]);
            float p3 = __expf(s[mg][h8 + 3]);
            float p4 = __expf(s[mg][h8 + 4]);
            float p5 = __expf(s[mg][h8 + 5]);
            float p6 = __expf(s[mg][h8 + 6]);
            float p7 = __expf(s[mg][h8 + 7]);
            l += ((p0 + p1) + (p2 + p3)) + ((p4 + p5) + (p6 + p7));
            unsigned int A0 = pk_trunc(p0, p1), A1 = pk_trunc(p2, p3);
            unsigned int A2 = pk_trunc(p4, p5), A3 = pk_trunc(p6, p7);
            // swap(D,S): D.hi <-> S.lo  =>  D=A0,S=A2: A0={A0.lo|A2.lo},
            // A2={A0.hi|A2.hi}  (exactly word0/word2)
            asm("v_permlane32_swap_b32 %0, %1" : "+v"(A0), "+v"(A2));
            asm("v_permlane32_swap_b32 %0, %1" : "+v"(A1), "+v"(A3));
            u32x4 pbw = { A0, A1, A2, A3 };
            bf16x8 pb = __builtin_bit_cast(bf16x8, pbw);
#pragma unroll
            for (int g = 0; g < 4; g++)
                acc[g] = __builtin_amdgcn_mfma_f32_32x32x16_bf16(vb[g * 4 + u], pb, acc[g], 0, 0, 0);
            // prefetch this chunk's V frags for the next tile (consumed next t)
#pragma unroll
            for (int g = 0; g < 4; g++)
                vb[g * 4 + u] = *(const bf16x8*)(vtn + (size_t)(g * 4 + u) * 512 + (size_t)lane * 8);
        }
        vtile = vtn;
    }

    // --- cross-wave merge, single [q][c] buffer, 4 serialized rounds ---
    l_s[(w * 2 + half) * 32 + q32] = l;
    for (int ww = 0; ww < 4; ww++) {
        if (w == ww) {
#pragma unroll
            for (int g = 0; g < 4; g++)
#pragma unroll
                for (int r = 0; r < 4; r++) {
                    // acc[g][4r+i] -> c = g*32 + 8r + 4*half + i
                    float* p = accs + q32 * 132 + g * 32 + r * 8 + half * 4;
                    f32x4 v4 = { acc[g][r*4+0], acc[g][r*4+1], acc[g][r*4+2], acc[g][r*4+3] };
                    if (ww == 0) *(f32x4*)p = v4;
                    else { f32x4 o = *(const f32x4*)p; *(f32x4*)p = o + v4; }
                }
        }
        __syncthreads();
    }

    // --- epilogue: 256 threads, q = tid&31, 16 channels each ---
    float gam = gamma[0];
    int q = tid & 31, cg = tid >> 5;
    float L = 0.f;
#pragma unroll
    for (int u = 0; u < 8; u++) L += l_s[u * 32 + q];
    float linv = 1.f / L;
#pragma unroll
    for (int cc = 0; cc < 16; cc++) {
        int c = cg * 16 + cc;
        size_t gi = ((size_t)(b * CV + c)) * NN + i0 + q;
        out[gi] = gam * accs[q * 132 + c] * linv + xh[gi];
    }
}

extern "C" void kernel_launch(void* const* d_in, const int* in_sizes, int n_in,
                              void* d_out, int out_size, void* d_ws, size_t ws_size,
                              hipStream_t stream)
{
    (void)in_sizes; (void)n_in; (void)out_size; (void)ws_size;
    const float* x  = (const float*)d_in[0];
    const float* xh = (const float*)d_in[1];
    const float* Wq = (const float*)d_in[2];
    const float* bq = (const float*)d_in[3];
    const float* Wk = (const float*)d_in[4];
    const float* bk = (const float*)d_in[5];
    const float* Wv = (const float*)d_in[6];
    const float* bv = (const float*)d_in[7];
    const float* gm = (const float*)d_in[8];
    float* out = (float*)d_out;

    char* ws = (char*)d_ws;
    unsigned short* qTb = (unsigned short*)ws;                      // 512 KB
    unsigned short* kTb = (unsigned short*)(ws + (512 << 10));      // 512 KB
    unsigned short* vB  = (unsigned short*)(ws + (1 << 20));        // 4 MB

    // 64 QK blocks + 256 V-MFMA blocks (one per 64-key vB tile)
    proj<<<320, 256, 0, stream>>>(x, Wq, bq, Wk, bk, xh, Wv, bv, qTb, kTb, vB);
    // 32 queries/block -> BB*128 = 512 blocks (R2 champion)
    flash_mfma<<<BB * 128, 256, 0, stream>>>(qTb, kTb, vB, xh, gm, out);
}

// Round 7
// 125.143 us; speedup vs baseline: 1.2767x; 1.0368x over previous
//
#include <hip/hip_runtime.h>

#define BB 4
#define NN 4096        // 64*64 spatial
#define CQK 64
#define DQ 16
#define CV 128

typedef __attribute__((ext_vector_type(8))) short bf16x8;
typedef __attribute__((ext_vector_type(4))) float f32x4;
typedef __attribute__((ext_vector_type(16))) float f32x16;
typedef __attribute__((ext_vector_type(8))) unsigned short u16x8;
typedef __attribute__((ext_vector_type(4))) unsigned int u32x4;

__device__ __forceinline__ unsigned short f2bf(float f) {
    unsigned int u = __builtin_bit_cast(unsigned int, f);
    u += 0x7FFFu + ((u >> 16) & 1u);   // RNE
    return (unsigned short)(u >> 16);
}
// truncation-pack two fp32 -> packed bf16x2 (v_perm_b32-foldable)
__device__ __forceinline__ unsigned int pk_trunc(float lo, float hi) {
    unsigned int a = __builtin_bit_cast(unsigned int, lo);
    unsigned int b = __builtin_bit_cast(unsigned int, hi);
    return (a >> 16) | (b & 0xFFFF0000u);
}

// ================= fused projections =================
// EXACT R2 champion proj (proj ~33us). R5's MFMA V-proj was 10us SLOWER:
// its per-lane Wv float4 loads were 512B-strided (32 L2 lines/instr,
// no LDS staging) -- reverted. Only change vs R2: qT is pre-scaled by
// log2(e) so flash can use raw v_exp_f32 (2^x) instead of expf.
// blocks 0..63:   Q/K projection (256 positions per block)
// blocks 64..575: V projection (2 blocks per 64-pos tile, 64 out-chans each)
__global__ __launch_bounds__(256, 4) void proj(
    const float* __restrict__ x,   // [B][64][N]
    const float* __restrict__ Wq, const float* __restrict__ bq,
    const float* __restrict__ Wk, const float* __restrict__ bk,
    const float* __restrict__ xh,  // [B][128][N]
    const float* __restrict__ Wv, const float* __restrict__ bv,
    unsigned short* __restrict__ qT, unsigned short* __restrict__ kT,
    unsigned short* __restrict__ vB)
{
    __shared__ __align__(16) float smem[8448];
    int tid = threadIdx.x;
    if (blockIdx.x >= 64) {
        // ---------- V projection ----------
        float* wvT = smem;            // [64 ci][66]
        float* xs  = smem + 4224;     // [64 ci][64 pos]
        float* bvs = smem + 8320;     // [64]
        int bid = blockIdx.x - 64;
        int pt = bid >> 1, h = bid & 1;
        int i0 = pt * 64;
        int b = i0 >> 12, ib = i0 & 4095;
        int co0 = h * 64;
        if (tid < 64) bvs[tid] = bv[co0 + tid];
        int cog = tid & 31, ig = tid >> 5;   // 2 out-chans, 8 positions
        float acc[8][2];
#pragma unroll
        for (int q = 0; q < 8; q++) { acc[q][0] = 0.f; acc[q][1] = 0.f; }

        for (int ch = 0; ch < 2; ch++) {
            for (int t = tid; t < 4096; t += 256) {
                int c = t & 63, col = t >> 6;
                wvT[c * 66 + col] = Wv[(size_t)(co0 + col) * CV + ch * 64 + c];
            }
            for (int t = tid; t < 4096; t += 256) {
                int il = t & 63, c = t >> 6;
                xs[c * 64 + il] = xh[((size_t)b * CV + ch * 64 + c) * NN + ib + il];
            }
            __syncthreads();
            for (int c = 0; c < 64; c++) {
                float2 w2 = *(const float2*)&wvT[c * 66 + cog * 2];
                float4 xa = *(const float4*)&xs[c * 64 + ig * 8];
                float4 xb = *(const float4*)&xs[c * 64 + ig * 8 + 4];
                float xv[8] = { xa.x, xa.y, xa.z, xa.w, xb.x, xb.y, xb.z, xb.w };
#pragma unroll
                for (int q = 0; q < 8; q++) {
                    acc[q][0] += xv[q] * w2.x;
                    acc[q][1] += xv[q] * w2.y;
                }
            }
            __syncthreads();
        }
        // swizzled store: vB per 64-key tile = [chunk/frag][lane][jj] A-frag
        // order for v_mfma_f32_32x32x16_bf16 (A = V, m=chan, k=key-in-chunk)
        int kt = ib >> 6;
        int hb = ig & 1, kc = ig >> 1;   // keys ig*8..ig*8+7 -> chunk kc, half hb
#pragma unroll
        for (int cc = 0; cc < 2; cc++) {
            int co = co0 + cog * 2 + cc;
            int g = co >> 5, cl = co & 31;
            float bb = bvs[cog * 2 + cc];
            u16x8 o;
#pragma unroll
            for (int jj = 0; jj < 8; jj++) o[jj] = f2bf(acc[jj][cc] + bb);
            size_t base = ((size_t)(b * 64 + kt)) * 8192
                        + (size_t)(((g * 4 + kc) * 64 + hb * 32 + cl)) * 8;
            *(u16x8*)(vB + base) = o;
        }
    } else {
        // ---------- Q/K projection ----------
        float* wqT = smem;          // [64 c][16 d]
        float* wkT = smem + 1024;
        float* bqs = smem + 2048;
        float* bks = smem + 2064;
        for (int t = tid; t < 1024; t += 256) {
            int c = t & 63, d = t >> 6;          // coalesced global read
            wqT[c * 16 + d] = Wq[d * CQK + c];
            wkT[c * 16 + d] = Wk[d * CQK + c];
        }
        if (tid < DQ) { bqs[tid] = bq[tid]; bks[tid] = bk[tid]; }
        __syncthreads();

        int gidx = blockIdx.x * 256 + tid;   // over B*N
        int b = gidx >> 12, i = gidx & 4095;
        float qa[DQ], ka[DQ];
#pragma unroll
        for (int d = 0; d < DQ; d++) { qa[d] = bqs[d]; ka[d] = bks[d]; }
        const float* xp = x + (size_t)b * CQK * NN + i;
        for (int c = 0; c < CQK; c++) {
            float xv = xp[(size_t)c * NN];
            const float4* wq4 = (const float4*)&wqT[c * DQ];
            const float4* wk4 = (const float4*)&wkT[c * DQ];
#pragma unroll
            for (int dd = 0; dd < 4; dd++) {
                float4 a = wq4[dd], e = wk4[dd];
                qa[dd*4+0] += a.x * xv; qa[dd*4+1] += a.y * xv;
                qa[dd*4+2] += a.z * xv; qa[dd*4+3] += a.w * xv;
                ka[dd*4+0] += e.x * xv; ka[dd*4+1] += e.y * xv;
                ka[dd*4+2] += e.z * xv; ka[dd*4+3] += e.w * xv;
            }
        }
        const float L2E = 1.44269504088896f;   // q pre-scaled: exp(s)=2^(s')
        u16x8 q0, q1, k0, k1;
#pragma unroll
        for (int dd = 0; dd < 8; dd++) {
            q0[dd] = f2bf(qa[dd] * L2E);  q1[dd] = f2bf(qa[8 + dd] * L2E);
            k0[dd] = f2bf(ka[dd]);        k1[dd] = f2bf(ka[8 + dd]);
        }
        u16x8* qo = (u16x8*)(qT + (size_t)gidx * DQ);
        u16x8* ko = (u16x8*)(kT + (size_t)gidx * DQ);
        qo[0] = q0; qo[1] = q1;
        ko[0] = k0; ko[1] = k1;
    }
}

// ================= MFMA flash attention, 32 queries/block =================
// R6/R7 on top of the R2 champion (flash ~35.5us, latency-serialization):
//  (a) 2-stage pipeline: pbs[4] holds P of tile t-1; iter t = QK(t) issue,
//      PV(t-1) (operands ready -- MFMA no longer waits on exp chain),
//      then exp/pack(t). V-reload slack grows by the pack phase. +16 VGPR.
//  (b) exp2 direct: qT pre-scaled by log2e, p = __builtin_amdgcn_exp2f(s)
//      (v_exp_f32, compiler-managed TRANS hazards) -- drops 64 v_mul/iter.
//  (c) batch-per-XCD: b = blockIdx&3 so each XCD's L2 caches ONE batch's
//      vB (1MB) instead of all four (4MB, thrash-borderline).
// Layouts unchanged and R2-verified: S^T=K.Q^T 32x32x16, C col=q row=key;
// P B-frag via pk_trunc + v_permlane32_swap_b32 (D.hi <-> S.lo).
// (256,2): do NOT raise min-waves (R7 spill lesson). 32q/block optimum.
__global__ __launch_bounds__(256, 2) void flash_mfma(
    const unsigned short* __restrict__ qTb,  // [B*N][16] bf16 (q pre-scaled)
    const unsigned short* __restrict__ kTb,  // [B*N][16] bf16
    const unsigned short* __restrict__ vB,   // swizzled bf16 (32x32 A-frag order)
    const float* __restrict__ xh,            // [B][128][N]
    const float* __restrict__ gamma,
    float* __restrict__ out)                 // [B][128][N]
{
    __shared__ __align__(16) float accs[32 * 132];   // [q 32][c pad132]
    __shared__ float l_s[4 * 2 * 32];                // [w][half][q]

    int tid = threadIdx.x;
    int w = tid >> 6, lane = tid & 63;
    int q32 = lane & 31, half = lane >> 5;
    int p = blockIdx.x;
    int b = p & 3;                            // batch-per-XCD (c)
    int i0 = (p >> 2) * 32;
    f32x16 zf16;
#pragma unroll
    for (int r = 0; r < 16; r++) zf16[r] = 0.f;

    // Q B-frag (32x32x16): B[k=half*8+j][n=q32]
    bf16x8 qa = *(const bf16x8*)(qTb + ((size_t)(b * NN + i0 + q32)) * DQ + half * 8);

    f32x16 acc[4];                            // O^T[c][q]: c = g*32+(reg&3)+8*(reg>>2)+4*half
#pragma unroll
    for (int g = 0; g < 4; g++) acc[g] = zf16;
    float l = 0.f;

    const unsigned short* vtile = vB + ((size_t)(b * 64 + w * 16)) * 8192;
    const unsigned short* kbase = kTb + ((size_t)(b * NN + w * 16 * 64)) * DQ;

    // prefetch tile 0: K A-frags (A[m=key=q32][k=half*8+j]) + 16 V A-frags
    bf16x8 kb[2], vb[16];
#pragma unroll
    for (int mg = 0; mg < 2; mg++)
        kb[mg] = *(const bf16x8*)(kbase + (size_t)(mg * 32 + q32) * DQ + half * 8);
#pragma unroll
    for (int i = 0; i < 16; i++)
        vb[i] = *(const bf16x8*)(vtile + (size_t)i * 512 + (size_t)lane * 8);

    // pack one 16-key chunk of s into pbs[U] (B-frag for PV), accumulate l
#define PACK_U(SV, U)                                                        \
    {                                                                        \
        const int h8 = ((U) & 1) * 8;                                        \
        float e0 = __builtin_amdgcn_exp2f(SV[h8 + 0]);                       \
        float e1 = __builtin_amdgcn_exp2f(SV[h8 + 1]);                       \
        float e2 = __builtin_amdgcn_exp2f(SV[h8 + 2]);                       \
        float e3 = __builtin_amdgcn_exp2f(SV[h8 + 3]);                       \
        float e4 = __builtin_amdgcn_exp2f(SV[h8 + 4]);                       \
        float e5 = __builtin_amdgcn_exp2f(SV[h8 + 5]);                       \
        float e6 = __builtin_amdgcn_exp2f(SV[h8 + 6]);                       \
        float e7 = __builtin_amdgcn_exp2f(SV[h8 + 7]);                       \
        l += ((e0 + e1) + (e2 + e3)) + ((e4 + e5) + (e6 + e7));              \
        unsigned int A0 = pk_trunc(e0, e1), A1 = pk_trunc(e2, e3);           \
        unsigned int A2 = pk_trunc(e4, e5), A3 = pk_trunc(e6, e7);           \
        asm("v_permlane32_swap_b32 %0, %1" : "+v"(A0), "+v"(A2));            \
        asm("v_permlane32_swap_b32 %0, %1" : "+v"(A1), "+v"(A3));            \
        pbs[U] = (u32x4){A0, A1, A2, A3};                                    \
    }

    // --- prologue (tile 0): QK + pack only, no PV yet ---
    u32x4 pbs[4];
    {
        f32x16 sa = __builtin_amdgcn_mfma_f32_32x32x16_bf16(kb[0], qa, zf16, 0, 0, 0);
        f32x16 sb = __builtin_amdgcn_mfma_f32_32x32x16_bf16(kb[1], qa, zf16, 0, 0, 0);
        const unsigned short* ktn = kbase + (size_t)64 * DQ;   // tile 1
#pragma unroll
        for (int mg = 0; mg < 2; mg++)
            kb[mg] = *(const bf16x8*)(ktn + (size_t)(mg * 32 + q32) * DQ + half * 8);
        PACK_U(sa, 0) PACK_U(sa, 1) PACK_U(sb, 2) PACK_U(sb, 3)
    }

    for (int t = 1; t < 16; t++) {
        // --- QK(t) issue first (kb prefetched last iter) ---
        f32x16 sa = __builtin_amdgcn_mfma_f32_32x32x16_bf16(kb[0], qa, zf16, 0, 0, 0);
        f32x16 sb = __builtin_amdgcn_mfma_f32_32x32x16_bf16(kb[1], qa, zf16, 0, 0, 0);
        const unsigned short* ktn = kbase + (size_t)(((t + 1) & 15) * 64) * DQ;
#pragma unroll
        for (int mg = 0; mg < 2; mg++)
            kb[mg] = *(const bf16x8*)(ktn + (size_t)(mg * 32 + q32) * DQ + half * 8);

        // --- PV(t-1): pbs/vb ready, no dependence on this iter's exp ---
        const unsigned short* vtn = vtile + 8192;   // tile t
        __builtin_amdgcn_s_setprio(1);
#pragma unroll
        for (int u = 0; u < 4; u++) {
            bf16x8 pb = __builtin_bit_cast(bf16x8, pbs[u]);
#pragma unroll
            for (int g = 0; g < 4; g++)
                acc[g] = __builtin_amdgcn_mfma_f32_32x32x16_bf16(vb[g * 4 + u], pb, acc[g], 0, 0, 0);
#pragma unroll
            for (int g = 0; g < 4; g++)
                vb[g * 4 + u] = *(const bf16x8*)(vtn + (size_t)(g * 4 + u) * 512 + (size_t)lane * 8);
        }
        __builtin_amdgcn_s_setprio(0);
        vtile = vtn;

        // --- pack(t) -> pbs for next iter's PV ---
        PACK_U(sa, 0) PACK_U(sa, 1) PACK_U(sb, 2) PACK_U(sb, 3)
    }

    // --- tail: PV(tile 15) ---
#pragma unroll
    for (int u = 0; u < 4; u++) {
        bf16x8 pb = __builtin_bit_cast(bf16x8, pbs[u]);
#pragma unroll
        for (int g = 0; g < 4; g++)
            acc[g] = __builtin_amdgcn_mfma_f32_32x32x16_bf16(vb[g * 4 + u], pb, acc[g], 0, 0, 0);
    }
#undef PACK_U

    // --- cross-wave merge, single [q][c] buffer, 4 serialized rounds ---
    l_s[(w * 2 + half) * 32 + q32] = l;
    for (int ww = 0; ww < 4; ww++) {
        if (w == ww) {
#pragma unroll
            for (int g = 0; g < 4; g++)
#pragma unroll
                for (int r = 0; r < 4; r++) {
                    // acc[g][4r+i] -> c = g*32 + 8r + 4*half + i
                    float* pp = accs + q32 * 132 + g * 32 + r * 8 + half * 4;
                    f32x4 v4 = { acc[g][r*4+0], acc[g][r*4+1], acc[g][r*4+2], acc[g][r*4+3] };
                    if (ww == 0) *(f32x4*)pp = v4;
                    else { f32x4 o = *(const f32x4*)pp; *(f32x4*)pp = o + v4; }
                }
        }
        __syncthreads();
    }

    // --- epilogue: 256 threads, q = tid&31, 16 channels each ---
    float gam = gamma[0];
    int q = tid & 31, cg = tid >> 5;
    float L = 0.f;
#pragma unroll
    for (int u = 0; u < 8; u++) L += l_s[u * 32 + q];
    float linv = 1.f / L;
#pragma unroll
    for (int cc = 0; cc < 16; cc++) {
        int c = cg * 16 + cc;
        size_t gi = ((size_t)(b * CV + c)) * NN + i0 + q;
        out[gi] = gam * accs[q * 132 + c] * linv + xh[gi];
    }
}

extern "C" void kernel_launch(void* const* d_in, const int* in_sizes, int n_in,
                              void* d_out, int out_size, void* d_ws, size_t ws_size,
                              hipStream_t stream)
{
    (void)in_sizes; (void)n_in; (void)out_size; (void)ws_size;
    const float* x  = (const float*)d_in[0];
    const float* xh = (const float*)d_in[1];
    const float* Wq = (const float*)d_in[2];
    const float* bq = (const float*)d_in[3];
    const float* Wk = (const float*)d_in[4];
    const float* bk = (const float*)d_in[5];
    const float* Wv = (const float*)d_in[6];
    const float* bv = (const float*)d_in[7];
    const float* gm = (const float*)d_in[8];
    float* out = (float*)d_out;

    char* ws = (char*)d_ws;
    unsigned short* qTb = (unsigned short*)ws;                      // 512 KB
    unsigned short* kTb = (unsigned short*)(ws + (512 << 10));      // 512 KB
    unsigned short* vB  = (unsigned short*)(ws + (1 << 20));        // 4 MB

    // R2 grid: 64 QK blocks + 512 V blocks
    proj<<<576, 256, 0, stream>>>(x, Wq, bq, Wk, bk, xh, Wv, bv, qTb, kTb, vB);
    // 32 queries/block -> BB*128 = 512 blocks
    flash_mfma<<<BB * 128, 256, 0, stream>>>(qTb, kTb, vB, xh, gm, out);
}

// Round 11
// 121.020 us; speedup vs baseline: 1.3202x; 1.0341x over previous
//
#include <hip/hip_runtime.h>

#define BB 4
#define NN 4096        // 64*64 spatial
#define CQK 64
#define DQ 16
#define CV 128

typedef __attribute__((ext_vector_type(8))) short bf16x8;
typedef __attribute__((ext_vector_type(4))) float f32x4;
typedef __attribute__((ext_vector_type(16))) float f32x16;
typedef __attribute__((ext_vector_type(8))) unsigned short u16x8;
typedef __attribute__((ext_vector_type(4))) unsigned int u32x4;

__device__ __forceinline__ unsigned short f2bf(float f) {
    unsigned int u = __builtin_bit_cast(unsigned int, f);
    u += 0x7FFFu + ((u >> 16) & 1u);   // RNE
    return (unsigned short)(u >> 16);
}
// truncation-pack two fp32 -> packed bf16x2 (v_perm_b32-foldable)
__device__ __forceinline__ unsigned int pk_trunc(float lo, float hi) {
    unsigned int a = __builtin_bit_cast(unsigned int, lo);
    unsigned int b = __builtin_bit_cast(unsigned int, hi);
    return (a >> 16) | (b & 0xFFFF0000u);
}

// ================= fused projections =================
// EXACT R2 champion proj (~10us actual; decomposition that claimed 42us was
// double-counting the harness reset tail -- proj never showed in top-5).
// R5/R8 MFMA V-proj alternatives slower or wrong; line closed.
// blocks 0..63: Q/K projection. blocks 64..575: V projection.
__global__ __launch_bounds__(256, 4) void proj(
    const float* __restrict__ x,   // [B][64][N]
    const float* __restrict__ Wq, const float* __restrict__ bq,
    const float* __restrict__ Wk, const float* __restrict__ bk,
    const float* __restrict__ xh,  // [B][128][N]
    const float* __restrict__ Wv, const float* __restrict__ bv,
    unsigned short* __restrict__ qT, unsigned short* __restrict__ kT,
    unsigned short* __restrict__ vB)
{
    __shared__ __align__(16) float smem[8448];
    int tid = threadIdx.x;
    if (blockIdx.x >= 64) {
        // ---------- V projection ----------
        float* wvT = smem;            // [64 ci][66]
        float* xs  = smem + 4224;     // [64 ci][64 pos]
        float* bvs = smem + 8320;     // [64]
        int bid = blockIdx.x - 64;
        int pt = bid >> 1, h = bid & 1;
        int i0 = pt * 64;
        int b = i0 >> 12, ib = i0 & 4095;
        int co0 = h * 64;
        if (tid < 64) bvs[tid] = bv[co0 + tid];
        int cog = tid & 31, ig = tid >> 5;   // 2 out-chans, 8 positions
        float acc[8][2];
#pragma unroll
        for (int q = 0; q < 8; q++) { acc[q][0] = 0.f; acc[q][1] = 0.f; }

        for (int ch = 0; ch < 2; ch++) {
            for (int t = tid; t < 4096; t += 256) {
                int c = t & 63, col = t >> 6;
                wvT[c * 66 + col] = Wv[(size_t)(co0 + col) * CV + ch * 64 + c];
            }
            for (int t = tid; t < 4096; t += 256) {
                int il = t & 63, c = t >> 6;
                xs[c * 64 + il] = xh[((size_t)b * CV + ch * 64 + c) * NN + ib + il];
            }
            __syncthreads();
            for (int c = 0; c < 64; c++) {
                float2 w2 = *(const float2*)&wvT[c * 66 + cog * 2];
                float4 xa = *(const float4*)&xs[c * 64 + ig * 8];
                float4 xb = *(const float4*)&xs[c * 64 + ig * 8 + 4];
                float xv[8] = { xa.x, xa.y, xa.z, xa.w, xb.x, xb.y, xb.z, xb.w };
#pragma unroll
                for (int q = 0; q < 8; q++) {
                    acc[q][0] += xv[q] * w2.x;
                    acc[q][1] += xv[q] * w2.y;
                }
            }
            __syncthreads();
        }
        // swizzled store: vB per 64-key tile = 16 A-frags for
        // v_mfma_f32_32x32x16_bf16 (A = V, m=chan, k=key-in-chunk)
        int kt = ib >> 6;
        int hb = ig & 1, kc = ig >> 1;   // keys ig*8..ig*8+7 -> chunk kc, half hb
#pragma unroll
        for (int cc = 0; cc < 2; cc++) {
            int co = co0 + cog * 2 + cc;
            int g = co >> 5, cl = co & 31;
            float bb = bvs[cog * 2 + cc];
            u16x8 o;
#pragma unroll
            for (int jj = 0; jj < 8; jj++) o[jj] = f2bf(acc[jj][cc] + bb);
            size_t base = ((size_t)(b * 64 + kt)) * 8192
                        + (size_t)(((g * 4 + kc) * 64 + hb * 32 + cl)) * 8;
            *(u16x8*)(vB + base) = o;
        }
    } else {
        // ---------- Q/K projection ----------
        float* wqT = smem;          // [64 c][16 d]
        float* wkT = smem + 1024;
        float* bqs = smem + 2048;
        float* bks = smem + 2064;
        for (int t = tid; t < 1024; t += 256) {
            int c = t & 63, d = t >> 6;          // coalesced global read
            wqT[c * 16 + d] = Wq[d * CQK + c];
            wkT[c * 16 + d] = Wk[d * CQK + c];
        }
        if (tid < DQ) { bqs[tid] = bq[tid]; bks[tid] = bk[tid]; }
        __syncthreads();

        int gidx = blockIdx.x * 256 + tid;   // over B*N
        int b = gidx >> 12, i = gidx & 4095;
        float qa[DQ], ka[DQ];
#pragma unroll
        for (int d = 0; d < DQ; d++) { qa[d] = bqs[d]; ka[d] = bks[d]; }
        const float* xp = x + (size_t)b * CQK * NN + i;
        for (int c = 0; c < CQK; c++) {
            float xv = xp[(size_t)c * NN];
            const float4* wq4 = (const float4*)&wqT[c * DQ];
            const float4* wk4 = (const float4*)&wkT[c * DQ];
#pragma unroll
            for (int dd = 0; dd < 4; dd++) {
                float4 a = wq4[dd], e = wk4[dd];
                qa[dd*4+0] += a.x * xv; qa[dd*4+1] += a.y * xv;
                qa[dd*4+2] += a.z * xv; qa[dd*4+3] += a.w * xv;
                ka[dd*4+0] += e.x * xv; ka[dd*4+1] += e.y * xv;
                ka[dd*4+2] += e.z * xv; ka[dd*4+3] += e.w * xv;
            }
        }
        u16x8 q0, q1, k0, k1;
#pragma unroll
        for (int dd = 0; dd < 8; dd++) {
            q0[dd] = f2bf(qa[dd]);     q1[dd] = f2bf(qa[8 + dd]);
            k0[dd] = f2bf(ka[dd]);     k1[dd] = f2bf(ka[8 + dd]);
        }
        u16x8* qo = (u16x8*)(qT + (size_t)gidx * DQ);
        u16x8* ko = (u16x8*)(kT + (size_t)gidx * DQ);
        qo[0] = q0; qo[1] = q1;
        ko[0] = k0; ko[1] = k1;
    }
}

// ================= MFMA flash attention, 32 queries/block =================
// R10 = EXACT R2 champion inner loop (every restructure attempt failed:
// R4 64q spilled, R7 SW-pipeline regressed, R9 reg-diet NaN'd) + two
// bit-exact-safe deltas:
//  (A) XCD swizzle: b = p&3, i0 = (p>>2)*32 (bijective; blockIdx%8 = XCD,
//      so each XCD is pinned to ONE batch's 1MB V working set in its L2).
//  (B) parallel merge: 4 private f32 LDS slabs + ONE barrier (was 4-round
//      serialized RMW with 4 barriers, 1 active wave per round). Epilogue
//      sums slabs in ascending w -- same order => bit-identical output.
// LDS 68.6KB -> still 2 blocks/CU (VGPR-bound anyway).
__global__ __launch_bounds__(256, 2) void flash_mfma(
    const unsigned short* __restrict__ qTb,  // [B*N][16] bf16
    const unsigned short* __restrict__ kTb,  // [B*N][16] bf16
    const unsigned short* __restrict__ vB,   // swizzled bf16 (32x32 A-frag order)
    const float* __restrict__ xh,            // [B][128][N]
    const float* __restrict__ gamma,
    float* __restrict__ out)                 // [B][128][N]
{
    __shared__ __align__(16) float accs[4 * 32 * 132];  // [w][q 32][c pad132]
    __shared__ float l_s[4 * 2 * 32];                   // [w][half][q]

    int tid = threadIdx.x;
    int w = tid >> 6, lane = tid & 63;
    int q32 = lane & 31, half = lane >> 5;
    int p = blockIdx.x;
    int b = p & 3;                            // (A) batch-per-XCD
    int i0 = (p >> 2) * 32;
    f32x16 zf16;
#pragma unroll
    for (int r = 0; r < 16; r++) zf16[r] = 0.f;

    // Q B-frag (32x32x16): B[k=half*8+j][n=q32]
    bf16x8 qa = *(const bf16x8*)(qTb + ((size_t)(b * NN + i0 + q32)) * DQ + half * 8);

    f32x16 acc[4];                            // O^T[c][q]: c = g*32+(reg&3)+8*(reg>>2)+4*half
#pragma unroll
    for (int g = 0; g < 4; g++) acc[g] = zf16;
    float l = 0.f;

    const unsigned short* vtile = vB + ((size_t)(b * 64 + w * 16)) * 8192;
    const unsigned short* kbase = kTb + ((size_t)(b * NN + w * 16 * 64)) * DQ;

    // prefetch tile 0: K A-frags (A[m=key=q32][k=half*8+j]) + 16 V A-frags
    bf16x8 kb[2], vb[16];
#pragma unroll
    for (int mg = 0; mg < 2; mg++)
        kb[mg] = *(const bf16x8*)(kbase + (size_t)(mg * 32 + q32) * DQ + half * 8);
#pragma unroll
    for (int i = 0; i < 16; i++)
        vb[i] = *(const bf16x8*)(vtile + (size_t)i * 512 + (size_t)lane * 8);

    for (int t = 0; t < 16; t++) {
        // --- S^T = K.Q^T : two 32x32x16 (keys 0-31, 32-63) x 32 queries ---
        f32x16 s[2];
        s[0] = __builtin_amdgcn_mfma_f32_32x32x16_bf16(kb[0], qa, zf16, 0, 0, 0);
        s[1] = __builtin_amdgcn_mfma_f32_32x32x16_bf16(kb[1], qa, zf16, 0, 0, 0);
        const unsigned short* ktn = kbase + (size_t)(((t + 1) & 15) * 64) * DQ;
#pragma unroll
        for (int mg = 0; mg < 2; mg++)
            kb[mg] = *(const bf16x8*)(ktn + (size_t)(mg * 32 + q32) * DQ + half * 8);

        const unsigned short* vtn = vtile + ((t < 15) ? 8192 : 0);
        // --- per 16-key chunk: exp -> in-register B-frag -> 4 PV MFMAs ---
#pragma unroll
        for (int u = 0; u < 4; u++) {
            const int mg = u >> 1, h8 = (u & 1) * 8;
            // lane (q,half) holds keys-in-chunk {0..3}+4h (p0-3), {8..11}+4h (p4-7)
            float p0 = __expf(s[mg][h8 + 0]);
            float p1 = __expf(s[mg][h8 + 1]);
            float p2 = __expf(s[mg][h8 + 2]);
            float p3 = __expf(s[mg][h8 + 3]);
            float p4 = __expf(s[mg][h8 + 4]);
            float p5 = __expf(s[mg][h8 + 5]);
            float p6 = __expf(s[mg][h8 + 6]);
            float p7 = __expf(s[mg][h8 + 7]);
            l += ((p0 + p1) + (p2 + p3)) + ((p4 + p5) + (p6 + p7));
            unsigned int A0 = pk_trunc(p0, p1), A1 = pk_trunc(p2, p3);
            unsigned int A2 = pk_trunc(p4, p5), A3 = pk_trunc(p6, p7);
            // swap(D,S): D.hi <-> S.lo  =>  D=A0,S=A2: A0={A0.lo|A2.lo},
            // A2={A0.hi|A2.hi}  (exactly word0/word2)
            asm("v_permlane32_swap_b32 %0, %1" : "+v"(A0), "+v"(A2));
            asm("v_permlane32_swap_b32 %0, %1" : "+v"(A1), "+v"(A3));
            u32x4 pbw = { A0, A1, A2, A3 };
            bf16x8 pb = __builtin_bit_cast(bf16x8, pbw);
#pragma unroll
            for (int g = 0; g < 4; g++)
                acc[g] = __builtin_amdgcn_mfma_f32_32x32x16_bf16(vb[g * 4 + u], pb, acc[g], 0, 0, 0);
            // prefetch this chunk's V frags for the next tile (consumed next t)
#pragma unroll
            for (int g = 0; g < 4; g++)
                vb[g * 4 + u] = *(const bf16x8*)(vtn + (size_t)(g * 4 + u) * 512 + (size_t)lane * 8);
        }
        vtile = vtn;
    }

    // --- (B) merge: each wave writes its own slab, ONE barrier ---
    l_s[(w * 2 + half) * 32 + q32] = l;
    {
        float* slab = accs + w * (32 * 132);
#pragma unroll
        for (int g = 0; g < 4; g++)
#pragma unroll
            for (int r = 0; r < 4; r++) {
                // acc[g][4r+i] -> c = g*32 + 8r + 4*half + i
                float* pp = slab + q32 * 132 + g * 32 + r * 8 + half * 4;
                f32x4 v4 = { acc[g][r*4+0], acc[g][r*4+1], acc[g][r*4+2], acc[g][r*4+3] };
                *(f32x4*)pp = v4;
            }
    }
    __syncthreads();

    // --- epilogue: 256 threads, q = tid&31, 16 channels each ---
    float gam = gamma[0];
    int q = tid & 31, cg = tid >> 5;
    float L = 0.f;
#pragma unroll
    for (int u = 0; u < 8; u++) L += l_s[u * 32 + q];
    float linv = 1.f / L;
    float o[16];
#pragma unroll
    for (int cc = 0; cc < 4; cc++) {
        // sum slabs in ascending w (same order as old serialized merge)
        f32x4 s0 = *(const f32x4*)(accs + 0 * 4224 + q * 132 + cg * 16 + cc * 4);
        f32x4 s1 = *(const f32x4*)(accs + 1 * 4224 + q * 132 + cg * 16 + cc * 4);
        f32x4 s2 = *(const f32x4*)(accs + 2 * 4224 + q * 132 + cg * 16 + cc * 4);
        f32x4 s3 = *(const f32x4*)(accs + 3 * 4224 + q * 132 + cg * 16 + cc * 4);
        f32x4 t4 = ((s0 + s1) + s2) + s3;
        o[cc * 4 + 0] = t4[0]; o[cc * 4 + 1] = t4[1];
        o[cc * 4 + 2] = t4[2]; o[cc * 4 + 3] = t4[3];
    }
#pragma unroll
    for (int cc = 0; cc < 16; cc++) {
        int c = cg * 16 + cc;
        size_t gi = ((size_t)(b * CV + c)) * NN + i0 + q;
        out[gi] = gam * o[cc] * linv + xh[gi];
    }
}

extern "C" void kernel_launch(void* const* d_in, const int* in_sizes, int n_in,
                              void* d_out, int out_size, void* d_ws, size_t ws_size,
                              hipStream_t stream)
{
    (void)in_sizes; (void)n_in; (void)out_size; (void)ws_size;
    const float* x  = (const float*)d_in[0];
    const float* xh = (const float*)d_in[1];
    const float* Wq = (const float*)d_in[2];
    const float* bq = (const float*)d_in[3];
    const float* Wk = (const float*)d_in[4];
    const float* bk = (const float*)d_in[5];
    const float* Wv = (const float*)d_in[6];
    const float* bv = (const float*)d_in[7];
    const float* gm = (const float*)d_in[8];
    float* out = (float*)d_out;

    char* ws = (char*)d_ws;
    unsigned short* qTb = (unsigned short*)ws;                      // 512 KB
    unsigned short* kTb = (unsigned short*)(ws + (512 << 10));      // 512 KB
    unsigned short* vB  = (unsigned short*)(ws + (1 << 20));        // 4 MB

    // R2 grid: 64 QK blocks + 512 V blocks
    proj<<<576, 256, 0, stream>>>(x, Wq, bq, Wk, bk, xh, Wv, bv, qTb, kTb, vB);
    // 32 queries/block -> BB*128 = 512 blocks
    flash_mfma<<<BB * 128, 256, 0, stream>>>(qTb, kTb, vB, xh, gm, out);
}